// Round 10
// baseline (119.309 us; speedup 1.0000x reference)
//
#include <hip/hip_runtime.h>

// AttEncoder fused: per-channel conv1d encoder + channel attention (C=4).
// w[b,i,j,t] = x_i(t)^T M_ij x_j(t) with M precomputed (16x16 per (i,j));
// only the v-conv runs at full N=512.
//
// R2..R9 history: occupancy/VGPR/run-length/LDS/NT/x4-scatter all tested.
// Surviving store model: per-CU coalesced-SEGMENT rate cap (~1/45cyc);
// bytes-per-contiguous-segment is the only lever. R5=256B/seg=2.9TB/s;
// fill=1KB/seg=6.9TB/s; R9's x4 = 4 scattered 256B segs = no gain.
// R10: one 512B contiguous segment per store instr: lane owns a t-PAIR,
//      float2 stores, no LDS/barriers. TT odd -> parity-shifted pairing on
//      odd f (block-uniform), edges by lane0/63; always 8B-aligned.

#define BB 4
#define CC 4
#define LL 32000
#define KK 16
#define ST 8
#define NN 512
#define TT 3999      // (LL-KK)/ST + 1
#define F3 1536
#define FC 32        // f per block in k2

// ---------------- k0: M[i][j][k][k2] = sum_f Wq[i,f,k] * Wk[j,f,k2] ----------
__global__ __launch_bounds__(256) void k0_M(const float* __restrict__ W,
                                            float* __restrict__ M) {
  const int i = blockIdx.x >> 2, j = blockIdx.x & 3;
  __shared__ float wq[NN * KK];
  __shared__ float wk[NN * KK];
  const int baseq = (i * F3 + NN) * KK;
  const int basek = (j * F3) * KK;
  for (int idx = threadIdx.x; idx < NN * KK; idx += 256) {
    wq[idx] = W[baseq + idx];
    wk[idx] = W[basek + idx];
  }
  __syncthreads();
  const int k = threadIdx.x >> 4, k2 = threadIdx.x & 15;
  float acc = 0.f;
  for (int f = 0; f < NN; ++f)
    acc = fmaf(wq[f * KK + k], wk[f * KK + k2], acc);
  M[((i * 4 + j) * 16 + k) * 16 + k2] = acc;
}

// ---------------- k1: A[b][t][i][j] = 0.5*(softmax_j(w) + delta_ij) ---------
template <int I>
__device__ __forceinline__ void k1_row(const float xr[4][16],
                                       const float* __restrict__ M,
                                       float* __restrict__ A, int bb, int t) {
  float w[4];
#pragma unroll
  for (int j = 0; j < 4; ++j) {
    const float* Mp = M + (I * 4 + j) * 256;
    float acc = 0.f;
#pragma unroll
    for (int k = 0; k < 16; ++k) {
      float y = 0.f;
#pragma unroll
      for (int k2 = 0; k2 < 16; ++k2)
        y = fmaf(Mp[k * 16 + k2], xr[j][k2], y);
      acc = fmaf(xr[I][k], y, acc);
    }
    w[j] = acc;
  }
  const float m = fmaxf(fmaxf(w[0], w[1]), fmaxf(w[2], w[3]));
  const float e0 = __expf(w[0] - m), e1 = __expf(w[1] - m);
  const float e2 = __expf(w[2] - m), e3 = __expf(w[3] - m);
  const float inv = 0.5f / (e0 + e1 + e2 + e3);
  float4 av;
  av.x = e0 * inv;
  av.y = e1 * inv;
  av.z = e2 * inv;
  av.w = e3 * inv;
  if (I == 0) av.x += 0.5f;
  if (I == 1) av.y += 0.5f;
  if (I == 2) av.z += 0.5f;
  if (I == 3) av.w += 0.5f;
  *reinterpret_cast<float4*>(A + ((bb * TT + t) * 4 + I) * 4) = av;
}

__global__ __launch_bounds__(256, 4) void k1_A(const float* __restrict__ x,
                                               const float* __restrict__ M,
                                               float* __restrict__ A) {
  const int bb = blockIdx.y;
  const int lane = threadIdx.x & 63;
  const int wv = threadIdx.x >> 6;
  const int t = blockIdx.x * 64 + lane;
  if (t >= TT) return;
  float xr[4][16];
#pragma unroll
  for (int c = 0; c < 4; ++c) {
    const float* xp = x + (bb * CC + c) * LL + t * ST;
#pragma unroll
    for (int k4 = 0; k4 < 16; k4 += 4) {
      const float4 v4 = *reinterpret_cast<const float4*>(xp + k4);
      xr[c][k4 + 0] = v4.x;
      xr[c][k4 + 1] = v4.y;
      xr[c][k4 + 2] = v4.z;
      xr[c][k4 + 3] = v4.w;
    }
  }
  if (wv == 0)      k1_row<0>(xr, M, A, bb, t);
  else if (wv == 1) k1_row<1>(xr, M, A, bb, t);
  else if (wv == 2) k1_row<2>(xr, M, A, bb, t);
  else              k1_row<3>(xr, M, A, bb, t);
}

// ---------------- k2: v-conv + mix + 512B-contiguous float2 stores ----------
// Lane owns t-pair; wave's 64 float2 stores cover 128 consecutive floats of
// ONE row -> one 512B segment per store instruction. v computed at 3 offsets
// d=0,1,2 (window 32 floats/c) so both parities are served from registers.
__global__ __launch_bounds__(256, 2) void k2_out(const float* __restrict__ x,
                                                 const float* __restrict__ W,
                                                 const float* __restrict__ A,
                                                 float* __restrict__ out) {
  const int tid = (int)threadIdx.x;
  const int ln = tid & 63;
  const int wv = tid >> 6;
  const int bb = blockIdx.x >> 3;
  const int t0w = (blockIdx.x & 7) * 512 + wv * 128;  // wave t-base (even)
  const int f0 = blockIdx.y * FC;
  const int t0 = t0w + 2 * ln;
  const int tcl = min(t0, TT - 1);

  // ---- x windows: 32 floats per c = [8*tcl, 8*tcl+32), clamped per-quad ----
  int off[8];
#pragma unroll
  for (int q = 0; q < 8; ++q) off[q] = min(8 * tcl + 4 * q, LL - 4);
  float xw[4][32];
#pragma unroll
  for (int c = 0; c < 4; ++c) {
    const float* xc = x + (bb * CC + c) * LL;
#pragma unroll
    for (int q = 0; q < 8; ++q) {
      const float4 v4 = *reinterpret_cast<const float4*>(xc + off[q]);
      xw[c][4 * q + 0] = v4.x;
      xw[c][4 * q + 1] = v4.y;
      xw[c][4 * q + 2] = v4.z;
      xw[c][4 * q + 3] = v4.w;
    }
  }

  // ---- A preload: 3 t-offsets x 4 i ----
  float4 a[3][4];
#pragma unroll
  for (int d = 0; d < 3; ++d) {
    const int td = min(t0 + d, TT - 1);
    const float4* ap = reinterpret_cast<const float4*>(A) + (bb * TT + td) * 4;
#pragma unroll
    for (int i = 0; i < 4; ++i) a[d][i] = ap[i];
  }

  for (int f = 0; f < FC; ++f) {
    const int fg = f0 + f;
    // v at d=0,1,2 for each channel; W rows are block-uniform -> s_load.
    float v[3][4];
#pragma unroll
    for (int c = 0; c < 4; ++c) {
      const float* wr = W + (c * F3 + 2 * NN + fg) * KK;
      float s0 = 0.f, s1 = 0.f, s2 = 0.f;
#pragma unroll
      for (int k = 0; k < 16; ++k) {
        const float wk = wr[k];
        s0 = fmaf(wk, xw[c][k], s0);
        s1 = fmaf(wk, xw[c][k + 8], s1);
        s2 = fmaf(wk, xw[c][k + 16], s2);
      }
      v[0][c] = s0;
      v[1][c] = s1;
      v[2][c] = s2;
    }
    float o[3][4];
#pragma unroll
    for (int d = 0; d < 3; ++d)
#pragma unroll
      for (int i = 0; i < 4; ++i)
        o[d][i] = fmaf(a[d][i].w, v[d][3],
                       fmaf(a[d][i].z, v[d][2],
                            fmaf(a[d][i].y, v[d][1], a[d][i].x * v[d][0])));

    const int par = fg & 1;  // block-uniform parity of row base
#pragma unroll
    for (int i = 0; i < 4; ++i) {
      float* op = out + (size_t)((bb * 4 + i) * NN + fg) * TT;
      if (!par) {
        // pairs (t0, t0+1): rowbase even, t0 even -> 8B aligned
        if (t0 + 1 < TT)
          *reinterpret_cast<float2*>(op + t0) = make_float2(o[0][i], o[1][i]);
        else if (t0 < TT)
          op[t0] = o[0][i];
      } else {
        // pairs (t0+1, t0+2): rowbase odd, t0+1 odd -> 8B aligned
        if (ln == 0) op[t0w] = o[0][i];  // wave-offset 0 edge
        if (t0 + 2 < TT)
          *reinterpret_cast<float2*>(op + t0 + 1) =
              make_float2(o[1][i], o[2][i]);
        else if (t0 + 1 < TT)
          op[t0 + 1] = o[1][i];
      }
    }
  }
}

extern "C" void kernel_launch(void* const* d_in, const int* in_sizes, int n_in,
                              void* d_out, int out_size, void* d_ws,
                              size_t ws_size, hipStream_t stream) {
  const float* x = (const float*)d_in[0];   // [B, C, L] fp32
  const float* W = (const float*)d_in[1];   // [C, F3, 1, K] fp32
  float* out = (float*)d_out;               // [B, C, N, T] fp32
  float* Mws = (float*)d_ws;                // 4096 floats
  float* Aws = Mws + 4 * 4 * 16 * 16;       // B*T*4*4 floats (~1 MB)

  hipLaunchKernelGGL(k0_M, dim3(16), dim3(256), 0, stream, W, Mws);
  hipLaunchKernelGGL(k1_A, dim3(63, BB), dim3(256), 0, stream, x, Mws, Aws);
  // grid: (4 b x 8 t-tiles of 512) x (16 f-tiles of 32); 256 thr, 2 blk/CU
  hipLaunchKernelGGL(k2_out, dim3(BB * 8, NN / FC), dim3(256), 0, stream, x, W,
                     Aws, out);
}

// Round 11
// 68.750 us; speedup vs baseline: 1.7354x; 1.7354x over previous
//
#include <hip/hip_runtime.h>

// AttEncoder fused: per-channel conv1d encoder + channel attention (C=4).
// w[b,i,j,t] = x_i(t)^T M_ij x_j(t) with M precomputed (16x16 per (i,j));
// only the v-conv runs at full N=512.
//
// R2..R10: occupancy/VGPR/run-length/LDS-W/NT/x4-scatter/float2-parity all
// tested. R9 x4 = scattered segments (no gain); R10 float2 test contaminated
// (3x conv FLOPs + VGPR overflow -> 119us). Surviving model: store path is
// limited by contiguous-segment issue rate; bytes-per-segment is the lever.
// R11: decouple: compute phase identical to R5 (t-per-lane, regs, s_load W)
//      but -> LDS; store phase streams 32 rows/group as ds_read_b128 +
//      global_store_dwordx4, 1KB contiguous 16B-ALIGNED segments (fill-clone).
//      Alignment: row base mod 4 == fg&3 -> LDS pre-shift s=(-fs)&3, lane63
//      does head/tail dwords. Raw s_barrier + lgkmcnt only (stores in flight).

#define BB 4
#define CC 4
#define LL 32000
#define KK 16
#define ST 8
#define NN 512
#define TT 3999      // (LL-KK)/ST + 1
#define F3 1536
#define FC 32        // f per block in k2
#define FG 8         // f per LDS group
#define TROW 260     // 256 + max shift(3) + pad

// ---------------- k0: M[i][j][k][k2] = sum_f Wq[i,f,k] * Wk[j,f,k2] ----------
__global__ __launch_bounds__(256) void k0_M(const float* __restrict__ W,
                                            float* __restrict__ M) {
  const int i = blockIdx.x >> 2, j = blockIdx.x & 3;
  __shared__ float wq[NN * KK];
  __shared__ float wk[NN * KK];
  const int baseq = (i * F3 + NN) * KK;
  const int basek = (j * F3) * KK;
  for (int idx = threadIdx.x; idx < NN * KK; idx += 256) {
    wq[idx] = W[baseq + idx];
    wk[idx] = W[basek + idx];
  }
  __syncthreads();
  const int k = threadIdx.x >> 4, k2 = threadIdx.x & 15;
  float acc = 0.f;
  for (int f = 0; f < NN; ++f)
    acc = fmaf(wq[f * KK + k], wk[f * KK + k2], acc);
  M[((i * 4 + j) * 16 + k) * 16 + k2] = acc;
}

// ---------------- k1: A[b][t][i][j] = 0.5*(softmax_j(w) + delta_ij) ---------
template <int I>
__device__ __forceinline__ void k1_row(const float xr[4][16],
                                       const float* __restrict__ M,
                                       float* __restrict__ A, int bb, int t) {
  float w[4];
#pragma unroll
  for (int j = 0; j < 4; ++j) {
    const float* Mp = M + (I * 4 + j) * 256;
    float acc = 0.f;
#pragma unroll
    for (int k = 0; k < 16; ++k) {
      float y = 0.f;
#pragma unroll
      for (int k2 = 0; k2 < 16; ++k2)
        y = fmaf(Mp[k * 16 + k2], xr[j][k2], y);
      acc = fmaf(xr[I][k], y, acc);
    }
    w[j] = acc;
  }
  const float m = fmaxf(fmaxf(w[0], w[1]), fmaxf(w[2], w[3]));
  const float e0 = __expf(w[0] - m), e1 = __expf(w[1] - m);
  const float e2 = __expf(w[2] - m), e3 = __expf(w[3] - m);
  const float inv = 0.5f / (e0 + e1 + e2 + e3);
  float4 av;
  av.x = e0 * inv;
  av.y = e1 * inv;
  av.z = e2 * inv;
  av.w = e3 * inv;
  if (I == 0) av.x += 0.5f;
  if (I == 1) av.y += 0.5f;
  if (I == 2) av.z += 0.5f;
  if (I == 3) av.w += 0.5f;
  *reinterpret_cast<float4*>(A + ((bb * TT + t) * 4 + I) * 4) = av;
}

__global__ __launch_bounds__(256, 4) void k1_A(const float* __restrict__ x,
                                               const float* __restrict__ M,
                                               float* __restrict__ A) {
  const int bb = blockIdx.y;
  const int lane = threadIdx.x & 63;
  const int wv = threadIdx.x >> 6;
  const int t = blockIdx.x * 64 + lane;
  if (t >= TT) return;
  float xr[4][16];
#pragma unroll
  for (int c = 0; c < 4; ++c) {
    const float* xp = x + (bb * CC + c) * LL + t * ST;
#pragma unroll
    for (int k4 = 0; k4 < 16; k4 += 4) {
      const float4 v4 = *reinterpret_cast<const float4*>(xp + k4);
      xr[c][k4 + 0] = v4.x;
      xr[c][k4 + 1] = v4.y;
      xr[c][k4 + 2] = v4.z;
      xr[c][k4 + 3] = v4.w;
    }
  }
  if (wv == 0)      k1_row<0>(xr, M, A, bb, t);
  else if (wv == 1) k1_row<1>(xr, M, A, bb, t);
  else if (wv == 2) k1_row<2>(xr, M, A, bb, t);
  else              k1_row<3>(xr, M, A, bb, t);
}

// ---------------- k2: compute->LDS, stream out as aligned 1KB segments ------
__global__ __launch_bounds__(256, 4) void k2_out(const float* __restrict__ x,
                                                 const float* __restrict__ W,
                                                 const float* __restrict__ A,
                                                 float* __restrict__ out) {
  __shared__ float ob[FG][4][TROW];   // 33280 B
  const int tid = (int)threadIdx.x;
  const int ln = tid & 63, wv = tid >> 6;
  const int bb = blockIdx.x >> 4;
  const int t0 = (blockIdx.x & 15) * 256;
  const int f0 = blockIdx.y * FC;
  const int t = t0 + tid;
  const int tcl = min(t, TT - 1);
  const int nvalid = min(256, TT - t0);

  // ---- x preload (R5 pattern) ----
  float xr[4][16];
#pragma unroll
  for (int c = 0; c < 4; ++c) {
    const float* xp = x + (bb * CC + c) * LL + tcl * ST;
#pragma unroll
    for (int k4 = 0; k4 < 16; k4 += 4) {
      const float4 v4 = *reinterpret_cast<const float4*>(xp + k4);
      xr[c][k4 + 0] = v4.x;
      xr[c][k4 + 1] = v4.y;
      xr[c][k4 + 2] = v4.z;
      xr[c][k4 + 3] = v4.w;
    }
  }
  // ---- A preload ----
  float4 a[4];
  {
    const float4* ap =
        reinterpret_cast<const float4*>(A + (bb * TT + tcl) * 16);
#pragma unroll
    for (int i = 0; i < 4; ++i) a[i] = ap[i];
  }

  for (int g = 0; g < FC / FG; ++g) {
    // ===== compute phase: FG f's into LDS (pre-shifted for alignment) =====
#pragma unroll
    for (int fs = 0; fs < FG; ++fs) {
      const int fg = f0 + g * FG + fs;
      const float* w0 = W + (0 * F3 + 2 * NN + fg) * KK;
      const float* w1 = W + (1 * F3 + 2 * NN + fg) * KK;
      const float* w2 = W + (2 * F3 + 2 * NN + fg) * KK;
      const float* w3 = W + (3 * F3 + 2 * NN + fg) * KK;
      float v0 = 0.f, v1 = 0.f, v2 = 0.f, v3 = 0.f;
#pragma unroll
      for (int k = 0; k < 16; ++k) {
        v0 = fmaf(w0[k], xr[0][k], v0);
        v1 = fmaf(w1[k], xr[1][k], v1);
        v2 = fmaf(w2[k], xr[2][k], v2);
        v3 = fmaf(w3[k], xr[3][k], v3);
      }
      const int s = (-fs) & 3;  // LDS shift so 16B LDS boundary == 16B out bdy
#pragma unroll
      for (int i = 0; i < 4; ++i) {
        const float o =
            fmaf(a[i].w, v3, fmaf(a[i].z, v2, fmaf(a[i].y, v1, a[i].x * v0)));
        ob[fs][i][tid + s] = o;
      }
    }
    asm volatile("s_waitcnt lgkmcnt(0)" ::: "memory");
    __builtin_amdgcn_s_barrier();

    // ===== store phase: 32 rows; wave wv -> 8 rows; 1KB aligned segments ====
#pragma unroll
    for (int rr = 0; rr < 8; ++rr) {
      const int fs = wv * 2 + (rr >> 2);
      const int ii = rr & 3;
      const int fg = f0 + g * FG + fs;
      const size_t rb = (size_t)((bb * 4 + ii) * NN + fg) * TT + t0;
      float* op = out + rb;
      const int head = fs & 3;  // == dwords until 16B boundary (rb%4 = -fg%4)
      if (head == 0) {
        const int tl = 4 * ln;
        const float4 v = *reinterpret_cast<const float4*>(&ob[fs][ii][tl]);
        if (tl + 3 < nvalid) {
          *reinterpret_cast<float4*>(op + tl) = v;
        } else {
          if (tl + 0 < nvalid) op[tl + 0] = v.x;
          if (tl + 1 < nvalid) op[tl + 1] = v.y;
          if (tl + 2 < nvalid) op[tl + 2] = v.z;
        }
      } else {
        if (ln < 63) {
          const int tl = head + 4 * ln;                 // global dword offset
          const float4 v =
              *reinterpret_cast<const float4*>(&ob[fs][ii][4 * ln + 4]);
          if (tl + 3 < nvalid) {
            *reinterpret_cast<float4*>(op + tl) = v;
          } else {
            if (tl + 0 < nvalid) op[tl + 0] = v.x;
            if (tl + 1 < nvalid) op[tl + 1] = v.y;
            if (tl + 2 < nvalid) op[tl + 2] = v.z;
          }
        } else {
          const int s = 4 - head;
#pragma unroll
          for (int d = 0; d < 3; ++d)
            if (d < head) op[d] = ob[fs][ii][d + s];
#pragma unroll
          for (int d = 0; d < 3; ++d) {
            const int tl = head + 252 + d;
            if (d < 4 - head && tl < nvalid) op[tl] = ob[fs][ii][tl + s];
          }
        }
      }
    }
    asm volatile("s_waitcnt lgkmcnt(0)" ::: "memory");
    __builtin_amdgcn_s_barrier();
  }
}

extern "C" void kernel_launch(void* const* d_in, const int* in_sizes, int n_in,
                              void* d_out, int out_size, void* d_ws,
                              size_t ws_size, hipStream_t stream) {
  const float* x = (const float*)d_in[0];   // [B, C, L] fp32
  const float* W = (const float*)d_in[1];   // [C, F3, 1, K] fp32
  float* out = (float*)d_out;               // [B, C, N, T] fp32
  float* Mws = (float*)d_ws;                // 4096 floats
  float* Aws = Mws + 4 * 4 * 16 * 16;       // B*T*4*4 floats (~1 MB)

  hipLaunchKernelGGL(k0_M, dim3(16), dim3(256), 0, stream, W, Mws);
  hipLaunchKernelGGL(k1_A, dim3(63, BB), dim3(256), 0, stream, x, Mws, Aws);
  // grid: (4 b x 16 t-tiles of 256) x (16 f-tiles of 32); 4 blocks/CU
  hipLaunchKernelGGL(k2_out, dim3(BB * 16, NN / FC), dim3(256), 0, stream, x,
                     W, Aws, out);
}

// Round 12
// 67.458 us; speedup vs baseline: 1.7686x; 1.0192x over previous
//
#include <hip/hip_runtime.h>

// AttEncoder fused: per-channel conv1d encoder + channel attention (C=4).
// w[b,i,j,t] = x_i(t)^T M_ij x_j(t) with M precomputed (16x16 per (i,j));
// only the v-conv runs at full N=512.
//
// R2..R11 summary: occupancy/VGPR/run-length/LDS-W/NT/x4-scatter/float2/
// LDS-2phase all tried. Surviving model: per-CU store TA width cap
// (~4B/lane-cyc): dword stores cap at ~2.5TB/s, dwordx4 at ~10 (HBM 6.9).
// Every wide-store attempt so far was sabotaged by edge divergence
// (R11: 3/4 rows took a lane-63 branch tree -> ~7 store instrs/row).
// R12: divergence-free x4 epilogue. LDS pre-shifted by s=(-fg)&3 so body
//      reads are 16B-aligned. head==0 rows: 1 aligned x4 instr (64 lanes).
//      head>0 rows: 63-lane aligned x4 body + lane63 stores TWO unaligned
//      x4 (gfx950 allows 4B-aligned x4; R9 verified) covering [252,256) and
//      [0,4) (overlaps rewrite identical values). Slow path only for the
//      last t-tile (64/1024 blocks). Barriers drain lgkmcnt only.

#define BB 4
#define CC 4
#define LL 32000
#define KK 16
#define ST 8
#define NN 512
#define TT 3999      // (LL-KK)/ST + 1
#define F3 1536
#define FC 32        // f per block in k2
#define FG 8         // f per LDS group
#define TROW 260     // 256 + max shift(3) + pad

// ---------------- k0: M[i][j][k][k2] = sum_f Wq[i,f,k] * Wk[j,f,k2] ----------
__global__ __launch_bounds__(256) void k0_M(const float* __restrict__ W,
                                            float* __restrict__ M) {
  const int i = blockIdx.x >> 2, j = blockIdx.x & 3;
  __shared__ float wq[NN * KK];
  __shared__ float wk[NN * KK];
  const int baseq = (i * F3 + NN) * KK;
  const int basek = (j * F3) * KK;
  for (int idx = threadIdx.x; idx < NN * KK; idx += 256) {
    wq[idx] = W[baseq + idx];
    wk[idx] = W[basek + idx];
  }
  __syncthreads();
  const int k = threadIdx.x >> 4, k2 = threadIdx.x & 15;
  float acc = 0.f;
  for (int f = 0; f < NN; ++f)
    acc = fmaf(wq[f * KK + k], wk[f * KK + k2], acc);
  M[((i * 4 + j) * 16 + k) * 16 + k2] = acc;
}

// ---------------- k1: A[b][t][i][j] = 0.5*(softmax_j(w) + delta_ij) ---------
template <int I>
__device__ __forceinline__ void k1_row(const float xr[4][16],
                                       const float* __restrict__ M,
                                       float* __restrict__ A, int bb, int t) {
  float w[4];
#pragma unroll
  for (int j = 0; j < 4; ++j) {
    const float* Mp = M + (I * 4 + j) * 256;
    float acc = 0.f;
#pragma unroll
    for (int k = 0; k < 16; ++k) {
      float y = 0.f;
#pragma unroll
      for (int k2 = 0; k2 < 16; ++k2)
        y = fmaf(Mp[k * 16 + k2], xr[j][k2], y);
      acc = fmaf(xr[I][k], y, acc);
    }
    w[j] = acc;
  }
  const float m = fmaxf(fmaxf(w[0], w[1]), fmaxf(w[2], w[3]));
  const float e0 = __expf(w[0] - m), e1 = __expf(w[1] - m);
  const float e2 = __expf(w[2] - m), e3 = __expf(w[3] - m);
  const float inv = 0.5f / (e0 + e1 + e2 + e3);
  float4 av;
  av.x = e0 * inv;
  av.y = e1 * inv;
  av.z = e2 * inv;
  av.w = e3 * inv;
  if (I == 0) av.x += 0.5f;
  if (I == 1) av.y += 0.5f;
  if (I == 2) av.z += 0.5f;
  if (I == 3) av.w += 0.5f;
  *reinterpret_cast<float4*>(A + ((bb * TT + t) * 4 + I) * 4) = av;
}

__global__ __launch_bounds__(256, 4) void k1_A(const float* __restrict__ x,
                                               const float* __restrict__ M,
                                               float* __restrict__ A) {
  const int bb = blockIdx.y;
  const int lane = threadIdx.x & 63;
  const int wv = threadIdx.x >> 6;
  const int t = blockIdx.x * 64 + lane;
  if (t >= TT) return;
  float xr[4][16];
#pragma unroll
  for (int c = 0; c < 4; ++c) {
    const float* xp = x + (bb * CC + c) * LL + t * ST;
#pragma unroll
    for (int k4 = 0; k4 < 16; k4 += 4) {
      const float4 v4 = *reinterpret_cast<const float4*>(xp + k4);
      xr[c][k4 + 0] = v4.x;
      xr[c][k4 + 1] = v4.y;
      xr[c][k4 + 2] = v4.z;
      xr[c][k4 + 3] = v4.w;
    }
  }
  if (wv == 0)      k1_row<0>(xr, M, A, bb, t);
  else if (wv == 1) k1_row<1>(xr, M, A, bb, t);
  else if (wv == 2) k1_row<2>(xr, M, A, bb, t);
  else              k1_row<3>(xr, M, A, bb, t);
}

// ---------------- k2: compute->LDS; divergence-free x4 store phase ----------
__global__ __launch_bounds__(256, 4) void k2_out(const float* __restrict__ x,
                                                 const float* __restrict__ W,
                                                 const float* __restrict__ A,
                                                 float* __restrict__ out) {
  __shared__ float ob[FG][4][TROW];   // 33280 B
  const int tid = (int)threadIdx.x;
  const int ln = tid & 63, wv = tid >> 6;
  const int bb = blockIdx.x >> 4;
  const int t0 = (blockIdx.x & 15) * 256;
  const int f0 = blockIdx.y * FC;
  const int t = t0 + tid;
  const int tcl = min(t, TT - 1);
  const int nvalid = min(256, TT - t0);

  // ---- x preload ----
  float xr[4][16];
#pragma unroll
  for (int c = 0; c < 4; ++c) {
    const float* xp = x + (bb * CC + c) * LL + tcl * ST;
#pragma unroll
    for (int k4 = 0; k4 < 16; k4 += 4) {
      const float4 v4 = *reinterpret_cast<const float4*>(xp + k4);
      xr[c][k4 + 0] = v4.x;
      xr[c][k4 + 1] = v4.y;
      xr[c][k4 + 2] = v4.z;
      xr[c][k4 + 3] = v4.w;
    }
  }
  // ---- A preload ----
  float4 a[4];
  {
    const float4* ap =
        reinterpret_cast<const float4*>(A + (bb * TT + tcl) * 16);
#pragma unroll
    for (int i = 0; i < 4; ++i) a[i] = ap[i];
  }

  for (int g = 0; g < FC / FG; ++g) {
    // ===== compute phase: FG f's into LDS, pre-shifted by s=(-fs)&3 =====
#pragma unroll 2
    for (int fs = 0; fs < FG; ++fs) {
      const int fg = f0 + g * FG + fs;
      const float* w0 = W + (0 * F3 + 2 * NN + fg) * KK;
      const float* w1 = W + (1 * F3 + 2 * NN + fg) * KK;
      const float* w2 = W + (2 * F3 + 2 * NN + fg) * KK;
      const float* w3 = W + (3 * F3 + 2 * NN + fg) * KK;
      float v0 = 0.f, v1 = 0.f, v2 = 0.f, v3 = 0.f;
#pragma unroll
      for (int k = 0; k < 16; ++k) {
        v0 = fmaf(w0[k], xr[0][k], v0);
        v1 = fmaf(w1[k], xr[1][k], v1);
        v2 = fmaf(w2[k], xr[2][k], v2);
        v3 = fmaf(w3[k], xr[3][k], v3);
      }
      const int s = (-fs) & 3;
#pragma unroll
      for (int i = 0; i < 4; ++i) {
        const float o =
            fmaf(a[i].w, v3, fmaf(a[i].z, v2, fmaf(a[i].y, v1, a[i].x * v0)));
        ob[fs][i][tid + s] = o;
      }
    }
    asm volatile("s_waitcnt lgkmcnt(0)" ::: "memory");
    __builtin_amdgcn_s_barrier();

    // ===== store phase: 32 rows; wave -> 8 rows; divergence-free x4 =====
    if (nvalid == 256) {
#pragma unroll
      for (int rr = 0; rr < 8; ++rr) {
        const int fs = wv * 2 + (rr >> 2);
        const int ii = rr & 3;
        const int fg = f0 + g * FG + fs;
        const int head = fs & 3;
        const int s = (-fs) & 3;
        float* op = out + (size_t)((bb * 4 + ii) * NN + fg) * TT + t0;
        if (head == 0) {
          const float4 v =
              *reinterpret_cast<const float4*>(&ob[fs][ii][4 * ln]);
          *reinterpret_cast<float4*>(op + 4 * ln) = v;
        } else if (ln < 63) {
          const int gofs = head + 4 * ln;          // body [head, head+252)
          const float4 v =
              *reinterpret_cast<const float4*>(&ob[fs][ii][gofs + s]);
          *reinterpret_cast<float4*>(op + gofs) = v;
        } else {
          float4 va, vb;                            // lane 63: two edge x4
          va.x = ob[fs][ii][252 + s];
          va.y = ob[fs][ii][253 + s];
          va.z = ob[fs][ii][254 + s];
          va.w = ob[fs][ii][255 + s];
          vb.x = ob[fs][ii][s + 0];
          vb.y = ob[fs][ii][s + 1];
          vb.z = ob[fs][ii][s + 2];
          vb.w = ob[fs][ii][s + 3];
          *reinterpret_cast<float4*>(op + 252) = va;  // [252,256)
          *reinterpret_cast<float4*>(op + 0) = vb;    // [0,4) overlap-same
        }
      }
    } else {
      // last t-tile (t0=3840, nvalid=159): predicated dword slow path
      for (int rr = 0; rr < 8; ++rr) {
        const int fs = wv * 2 + (rr >> 2);
        const int ii = rr & 3;
        const int fg = f0 + g * FG + fs;
        const int head = fs & 3;
        const int s = (-fs) & 3;
        float* op = out + (size_t)((bb * 4 + ii) * NN + fg) * TT + t0;
        const int g0 = head + 4 * ln;
#pragma unroll
        for (int d = 0; d < 4; ++d)
          if (g0 + d < nvalid) op[g0 + d] = ob[fs][ii][g0 + d + s];
        if (ln == 63) {
#pragma unroll
          for (int d = 0; d < 3; ++d)
            if (d < head) op[d] = ob[fs][ii][d + s];
        }
      }
    }
    asm volatile("s_waitcnt lgkmcnt(0)" ::: "memory");
    __builtin_amdgcn_s_barrier();
  }
}

extern "C" void kernel_launch(void* const* d_in, const int* in_sizes, int n_in,
                              void* d_out, int out_size, void* d_ws,
                              size_t ws_size, hipStream_t stream) {
  const float* x = (const float*)d_in[0];   // [B, C, L] fp32
  const float* W = (const float*)d_in[1];   // [C, F3, 1, K] fp32
  float* out = (float*)d_out;               // [B, C, N, T] fp32
  float* Mws = (float*)d_ws;                // 4096 floats
  float* Aws = Mws + 4 * 4 * 16 * 16;       // B*T*4*4 floats (~1 MB)

  hipLaunchKernelGGL(k0_M, dim3(16), dim3(256), 0, stream, W, Mws);
  hipLaunchKernelGGL(k1_A, dim3(63, BB), dim3(256), 0, stream, x, Mws, Aws);
  // grid: (4 b x 16 t-tiles of 256) x (16 f-tiles of 32); 4 blocks/CU
  hipLaunchKernelGGL(k2_out, dim3(BB * 16, NN / FC), dim3(256), 0, stream, x,
                     W, Aws, out);
}

// Round 13
// 61.159 us; speedup vs baseline: 1.9508x; 1.1030x over previous
//
#include <hip/hip_runtime.h>

// AttEncoder fused: per-channel conv1d encoder + channel attention (C=4).
// w[b,i,j,t] = x_i(t)^T M_ij x_j(t) with M precomputed (16x16 per (i,j));
// only the v-conv runs at full N=512.
//
// R2..R12: store width/alignment/segments/NT/LDS-2phase all falsified.
// Surviving model from invariants: per-wave outstanding-store DEPTH ~= 1.
// Cause: per-f 64-bit address recompute into reused VGPRs (+ spills when
// VGPR-starved: R1 WRITE_SIZE +3.5MB, R10 +8MB scratch traffic) forces
// s_waitcnt vmcnt(~0) every iteration. Fill kernel (VGPR 8, unrolled,
// pointer-stride addressing) keeps depth >=4 -> 6.9 TB/s.
// R13: pointer-bump stores (4 persistent row ptrs, += TT per f), unroll 2
//      (8 o-temps live -> depth up to 8), tail-free hot path, VGPR ~110
//      (no spill) at __launch_bounds__(256,4).

#define BB 4
#define CC 4
#define LL 32000
#define KK 16
#define ST 8
#define NN 512
#define TT 3999      // (LL-KK)/ST + 1
#define F3 1536
#define FC 32        // f per block in k2

// ---------------- k0: M[i][j][k][k2] = sum_f Wq[i,f,k] * Wk[j,f,k2] ----------
__global__ __launch_bounds__(256) void k0_M(const float* __restrict__ W,
                                            float* __restrict__ M) {
  const int i = blockIdx.x >> 2, j = blockIdx.x & 3;
  __shared__ float wq[NN * KK];
  __shared__ float wk[NN * KK];
  const int baseq = (i * F3 + NN) * KK;
  const int basek = (j * F3) * KK;
  for (int idx = threadIdx.x; idx < NN * KK; idx += 256) {
    wq[idx] = W[baseq + idx];
    wk[idx] = W[basek + idx];
  }
  __syncthreads();
  const int k = threadIdx.x >> 4, k2 = threadIdx.x & 15;
  float acc = 0.f;
  for (int f = 0; f < NN; ++f)
    acc = fmaf(wq[f * KK + k], wk[f * KK + k2], acc);
  M[((i * 4 + j) * 16 + k) * 16 + k2] = acc;
}

// ---------------- k1: A[b][t][i][j] = 0.5*(softmax_j(w) + delta_ij) ---------
template <int I>
__device__ __forceinline__ void k1_row(const float xr[4][16],
                                       const float* __restrict__ M,
                                       float* __restrict__ A, int bb, int t) {
  float w[4];
#pragma unroll
  for (int j = 0; j < 4; ++j) {
    const float* Mp = M + (I * 4 + j) * 256;
    float acc = 0.f;
#pragma unroll
    for (int k = 0; k < 16; ++k) {
      float y = 0.f;
#pragma unroll
      for (int k2 = 0; k2 < 16; ++k2)
        y = fmaf(Mp[k * 16 + k2], xr[j][k2], y);
      acc = fmaf(xr[I][k], y, acc);
    }
    w[j] = acc;
  }
  const float m = fmaxf(fmaxf(w[0], w[1]), fmaxf(w[2], w[3]));
  const float e0 = __expf(w[0] - m), e1 = __expf(w[1] - m);
  const float e2 = __expf(w[2] - m), e3 = __expf(w[3] - m);
  const float inv = 0.5f / (e0 + e1 + e2 + e3);
  float4 av;
  av.x = e0 * inv;
  av.y = e1 * inv;
  av.z = e2 * inv;
  av.w = e3 * inv;
  if (I == 0) av.x += 0.5f;
  if (I == 1) av.y += 0.5f;
  if (I == 2) av.z += 0.5f;
  if (I == 3) av.w += 0.5f;
  *reinterpret_cast<float4*>(A + ((bb * TT + t) * 4 + I) * 4) = av;
}

__global__ __launch_bounds__(256, 4) void k1_A(const float* __restrict__ x,
                                               const float* __restrict__ M,
                                               float* __restrict__ A) {
  const int bb = blockIdx.y;
  const int lane = threadIdx.x & 63;
  const int wv = threadIdx.x >> 6;
  const int t = blockIdx.x * 64 + lane;
  if (t >= TT) return;
  float xr[4][16];
#pragma unroll
  for (int c = 0; c < 4; ++c) {
    const float* xp = x + (bb * CC + c) * LL + t * ST;
#pragma unroll
    for (int k4 = 0; k4 < 16; k4 += 4) {
      const float4 v4 = *reinterpret_cast<const float4*>(xp + k4);
      xr[c][k4 + 0] = v4.x;
      xr[c][k4 + 1] = v4.y;
      xr[c][k4 + 2] = v4.z;
      xr[c][k4 + 3] = v4.w;
    }
  }
  if (wv == 0)      k1_row<0>(xr, M, A, bb, t);
  else if (wv == 1) k1_row<1>(xr, M, A, bb, t);
  else if (wv == 2) k1_row<2>(xr, M, A, bb, t);
  else              k1_row<3>(xr, M, A, bb, t);
}

// ---------------- k2: v-conv + mix; pointer-bump deep-pipelined stores ------
__global__ __launch_bounds__(256, 4) void k2_out(const float* __restrict__ x,
                                                 const float* __restrict__ W,
                                                 const float* __restrict__ A,
                                                 float* __restrict__ out) {
  const int tid = (int)threadIdx.x;
  const int bb = blockIdx.x >> 4;
  const int t0 = (blockIdx.x & 15) * 256;
  const int f0 = blockIdx.y * FC;
  const int t = t0 + tid;
  const int tcl = min(t, TT - 1);

  // ---- x preload ----
  float xr[4][16];
#pragma unroll
  for (int c = 0; c < 4; ++c) {
    const float* xp = x + (bb * CC + c) * LL + tcl * ST;
#pragma unroll
    for (int k4 = 0; k4 < 16; k4 += 4) {
      const float4 v4 = *reinterpret_cast<const float4*>(xp + k4);
      xr[c][k4 + 0] = v4.x;
      xr[c][k4 + 1] = v4.y;
      xr[c][k4 + 2] = v4.z;
      xr[c][k4 + 3] = v4.w;
    }
  }
  // ---- A preload ----
  float4 a[4];
  {
    const float4* ap =
        reinterpret_cast<const float4*>(A + (bb * TT + tcl) * 16);
#pragma unroll
    for (int i = 0; i < 4; ++i) a[i] = ap[i];
  }

  // ---- persistent row pointers (bumped by TT per f; no per-iter addr math)
  float* op0 = out + (size_t)((bb * 4 + 0) * NN + f0) * TT + tcl;
  float* op1 = out + (size_t)((bb * 4 + 1) * NN + f0) * TT + tcl;
  float* op2 = out + (size_t)((bb * 4 + 2) * NN + f0) * TT + tcl;
  float* op3 = out + (size_t)((bb * 4 + 3) * NN + f0) * TT + tcl;
  const float* wp0 = W + (0 * F3 + 2 * NN + f0) * KK;
  const float* wp1 = W + (1 * F3 + 2 * NN + f0) * KK;
  const float* wp2 = W + (2 * F3 + 2 * NN + f0) * KK;
  const float* wp3 = W + (3 * F3 + 2 * NN + f0) * KK;

  if (t0 + 256 <= TT) {
    // hot path: every lane stores, no predication
#pragma unroll 2
    for (int f = 0; f < FC; ++f) {
      float v0 = 0.f, v1 = 0.f, v2 = 0.f, v3 = 0.f;
#pragma unroll
      for (int k = 0; k < 16; ++k) {
        v0 = fmaf(wp0[k], xr[0][k], v0);
        v1 = fmaf(wp1[k], xr[1][k], v1);
        v2 = fmaf(wp2[k], xr[2][k], v2);
        v3 = fmaf(wp3[k], xr[3][k], v3);
      }
      const float q0 =
          fmaf(a[0].w, v3, fmaf(a[0].z, v2, fmaf(a[0].y, v1, a[0].x * v0)));
      const float q1 =
          fmaf(a[1].w, v3, fmaf(a[1].z, v2, fmaf(a[1].y, v1, a[1].x * v0)));
      const float q2 =
          fmaf(a[2].w, v3, fmaf(a[2].z, v2, fmaf(a[2].y, v1, a[2].x * v0)));
      const float q3 =
          fmaf(a[3].w, v3, fmaf(a[3].z, v2, fmaf(a[3].y, v1, a[3].x * v0)));
      *op0 = q0;
      *op1 = q1;
      *op2 = q2;
      *op3 = q3;
      op0 += TT;
      op1 += TT;
      op2 += TT;
      op3 += TT;
      wp0 += KK;
      wp1 += KK;
      wp2 += KK;
      wp3 += KK;
    }
  } else {
    // tail t-tile: predicated stores
    const bool ok = t < TT;
#pragma unroll 2
    for (int f = 0; f < FC; ++f) {
      float v0 = 0.f, v1 = 0.f, v2 = 0.f, v3 = 0.f;
#pragma unroll
      for (int k = 0; k < 16; ++k) {
        v0 = fmaf(wp0[k], xr[0][k], v0);
        v1 = fmaf(wp1[k], xr[1][k], v1);
        v2 = fmaf(wp2[k], xr[2][k], v2);
        v3 = fmaf(wp3[k], xr[3][k], v3);
      }
      const float q0 =
          fmaf(a[0].w, v3, fmaf(a[0].z, v2, fmaf(a[0].y, v1, a[0].x * v0)));
      const float q1 =
          fmaf(a[1].w, v3, fmaf(a[1].z, v2, fmaf(a[1].y, v1, a[1].x * v0)));
      const float q2 =
          fmaf(a[2].w, v3, fmaf(a[2].z, v2, fmaf(a[2].y, v1, a[2].x * v0)));
      const float q3 =
          fmaf(a[3].w, v3, fmaf(a[3].z, v2, fmaf(a[3].y, v1, a[3].x * v0)));
      if (ok) {
        *op0 = q0;
        *op1 = q1;
        *op2 = q2;
        *op3 = q3;
      }
      op0 += TT;
      op1 += TT;
      op2 += TT;
      op3 += TT;
      wp0 += KK;
      wp1 += KK;
      wp2 += KK;
      wp3 += KK;
    }
  }
}

extern "C" void kernel_launch(void* const* d_in, const int* in_sizes, int n_in,
                              void* d_out, int out_size, void* d_ws,
                              size_t ws_size, hipStream_t stream) {
  const float* x = (const float*)d_in[0];   // [B, C, L] fp32
  const float* W = (const float*)d_in[1];   // [C, F3, 1, K] fp32
  float* out = (float*)d_out;               // [B, C, N, T] fp32
  float* Mws = (float*)d_ws;                // 4096 floats
  float* Aws = Mws + 4 * 4 * 16 * 16;       // B*T*4*4 floats (~1 MB)

  hipLaunchKernelGGL(k0_M, dim3(16), dim3(256), 0, stream, W, Mws);
  hipLaunchKernelGGL(k1_A, dim3(63, BB), dim3(256), 0, stream, x, Mws, Aws);
  // grid: (4 b x 16 t-tiles of 256) x (16 f-tiles of 32); 4 blocks/CU
  hipLaunchKernelGGL(k2_out, dim3(BB * 16, NN / FC), dim3(256), 0, stream, x,
                     W, Aws, out);
}